// Round 4
// baseline (101.717 us; speedup 1.0000x reference)
//
#include <hip/hip_runtime.h>
#include <math.h>

#define ALPHA 0.7f
#define BETTA 0.3f
#define EPS   1e-8f

// native clang vector (HIP float4 is a class — nontemporal builtin rejects it)
typedef float vfloat4 __attribute__((ext_vector_type(4)));

__device__ __forceinline__ void row_contrib(float x1, float y1, float z1,
                                            float x2, float y2, float z2,
                                            float& a0, float& a1, float& a2,
                                            float& ac) {
    float q1 = x1 * x1 + y1 * y1 + z1 * z1;
    float m = (q1 > EPS * EPS) ? 1.0f : 0.0f;
    float inv1 = (q1 > 0.0f) ? rsqrtf(q1) : 0.0f;
    float n1x = x1 * inv1, n1y = y1 * inv1, n1z = z1 * inv1;

    float q2 = x2 * x2 + y2 * y2 + z2 * z2;
    float inv2 = (q2 > 0.0f) ? rsqrtf(q2) : 0.0f;
    float u2x = x2 * inv2, u2y = y2 * inv2, u2z = z2 * inv2;

    float c = n1x * u2x + n1y * u2y + n1z * u2z;
    c = fminf(1.0f, fmaxf(-1.0f, c));
    float sin_a = sqrtf(fmaxf(0.0f, 1.0f - c * c));
    float cm1 = c - 1.0f;

    float d = n1x * x2 + n1y * y2 + n1z * z2;
    float wx = x2 - n1x * d, wy = y2 - n1y * d, wz = z2 - n1z * d;
    float wq = wx * wx + wy * wy + wz * wz;
    float invw = (wq > 0.0f) ? rsqrtf(wq) : 0.0f;
    float n2x = wx * invw, n2y = wy * invw, n2z = wz * invw;

    float s1 = n1x + n1y + n1z;
    float s2 = n2x + n2y + n2z;

    float tax = sin_a * (n2x * s1 - n1x * s2);
    float tay = sin_a * (n2y * s1 - n1y * s2);
    float taz = sin_a * (n2z * s1 - n1z * s2);

    float tbx = cm1 * (n1x * s1 + n2x * s2);
    float tby = cm1 * (n1y * s1 + n2y * s2);
    float tbz = cm1 * (n1z * s1 + n2z * s2);

    a0 += (ALPHA * tax * tax + BETTA * tbx * tbx) * m;
    a1 += (ALPHA * tay * tay + BETTA * tby * tby) * m;
    a2 += (ALPHA * taz * taz + BETTA * tbz * tbz) * m;
    ac += m;
}

// Stage 1: 8 rows/thread (6 nontemporal 16B loads per input, all issued up
// front for memory-level parallelism). 1024 blocks for N=2^21.
__global__ __launch_bounds__(256) void trl_reduce(const float* __restrict__ v1,
                                                  const float* __restrict__ v2,
                                                  float4* __restrict__ ws,
                                                  int n_rows) {
    int tid = blockIdx.x * blockDim.x + threadIdx.x;
    long row0 = (long)tid * 8;

    float a0 = 0.0f, a1 = 0.0f, a2 = 0.0f, ac = 0.0f;

    if (row0 + 7 < n_rows) {
        const vfloat4* p1 = (const vfloat4*)(v1 + row0 * 3);
        const vfloat4* p2 = (const vfloat4*)(v2 + row0 * 3);
        vfloat4 A[6], B[6];
#pragma unroll
        for (int i = 0; i < 6; ++i) A[i] = __builtin_nontemporal_load(p1 + i);
#pragma unroll
        for (int i = 0; i < 6; ++i) B[i] = __builtin_nontemporal_load(p2 + i);

        row_contrib(A[0].x, A[0].y, A[0].z, B[0].x, B[0].y, B[0].z, a0, a1, a2, ac);
        row_contrib(A[0].w, A[1].x, A[1].y, B[0].w, B[1].x, B[1].y, a0, a1, a2, ac);
        row_contrib(A[1].z, A[1].w, A[2].x, B[1].z, B[1].w, B[2].x, a0, a1, a2, ac);
        row_contrib(A[2].y, A[2].z, A[2].w, B[2].y, B[2].z, B[2].w, a0, a1, a2, ac);
        row_contrib(A[3].x, A[3].y, A[3].z, B[3].x, B[3].y, B[3].z, a0, a1, a2, ac);
        row_contrib(A[3].w, A[4].x, A[4].y, B[3].w, B[4].x, B[4].y, a0, a1, a2, ac);
        row_contrib(A[4].z, A[4].w, A[5].x, B[4].z, B[4].w, B[5].x, a0, a1, a2, ac);
        row_contrib(A[5].y, A[5].z, A[5].w, B[5].y, B[5].z, B[5].w, a0, a1, a2, ac);
    } else {
        for (long r = row0; r < n_rows && r < row0 + 8; ++r) {
            const float* q1 = v1 + r * 3;
            const float* q2 = v2 + r * 3;
            row_contrib(q1[0], q1[1], q1[2], q2[0], q2[1], q2[2], a0, a1, a2, ac);
        }
    }

    // wave-64 shuffle reduction
    for (int off = 32; off > 0; off >>= 1) {
        a0 += __shfl_down(a0, off, 64);
        a1 += __shfl_down(a1, off, 64);
        a2 += __shfl_down(a2, off, 64);
        ac += __shfl_down(ac, off, 64);
    }

    __shared__ float smem[4][4];
    int lane = threadIdx.x & 63;
    int wave = threadIdx.x >> 6;
    if (lane == 0) {
        smem[wave][0] = a0;
        smem[wave][1] = a1;
        smem[wave][2] = a2;
        smem[wave][3] = ac;
    }
    __syncthreads();
    if (threadIdx.x == 0) {
        float4 t;
        t.x = smem[0][0] + smem[1][0] + smem[2][0] + smem[3][0];
        t.y = smem[0][1] + smem[1][1] + smem[2][1] + smem[3][1];
        t.z = smem[0][2] + smem[1][2] + smem[2][2] + smem[3][2];
        t.w = smem[0][3] + smem[1][3] + smem[2][3] + smem[3][3];
        ws[blockIdx.x] = t;  // one 16B store per block
    }
}

// Stage 2: one 256-thread block; threads stride over the float4 partials.
__global__ __launch_bounds__(256) void trl_final(const float4* __restrict__ ws,
                                                 float* __restrict__ out,
                                                 int nblocks) {
    float s0 = 0.0f, s1 = 0.0f, s2 = 0.0f, sc = 0.0f;
    for (int i = threadIdx.x; i < nblocks; i += 256) {
        float4 t = ws[i];
        s0 += t.x; s1 += t.y; s2 += t.z; sc += t.w;
    }
    for (int off = 32; off > 0; off >>= 1) {
        s0 += __shfl_down(s0, off, 64);
        s1 += __shfl_down(s1, off, 64);
        s2 += __shfl_down(s2, off, 64);
        sc += __shfl_down(sc, off, 64);
    }
    __shared__ float smem[4][4];
    int lane = threadIdx.x & 63;
    int wave = threadIdx.x >> 6;
    if (lane == 0) {
        smem[wave][0] = s0;
        smem[wave][1] = s1;
        smem[wave][2] = s2;
        smem[wave][3] = sc;
    }
    __syncthreads();
    if (threadIdx.x < 3) {
        float num = smem[0][threadIdx.x] + smem[1][threadIdx.x] +
                    smem[2][threadIdx.x] + smem[3][threadIdx.x];
        float cnt = smem[0][3] + smem[1][3] + smem[2][3] + smem[3][3];
        cnt = fmaxf(cnt, 1.0f);
        float v = num / cnt;
        if (isnan(v)) v = 0.0f;
        else if (isinf(v)) v = (v > 0.0f) ? 0.1f : -0.1f;
        out[threadIdx.x] = v;
    }
}

extern "C" void kernel_launch(void* const* d_in, const int* in_sizes, int n_in,
                              void* d_out, int out_size, void* d_ws, size_t ws_size,
                              hipStream_t stream) {
    const float* v1 = (const float*)d_in[0];
    const float* v2 = (const float*)d_in[1];
    float* out = (float*)d_out;
    float4* ws = (float4*)d_ws;

    int n_rows = in_sizes[0] / 3;

    int block = 256;
    int groups = (n_rows + 7) / 8;            // rows per thread = 8
    int grid = (groups + block - 1) / block;  // 1024 blocks for N=2^21

    trl_reduce<<<grid, block, 0, stream>>>(v1, v2, ws, n_rows);
    trl_final<<<1, 256, 0, stream>>>(ws, out, grid);
}

// Round 5
// 95.809 us; speedup vs baseline: 1.0617x; 1.0617x over previous
//
#include <hip/hip_runtime.h>
#include <math.h>

#define ALPHA 0.7f
#define BETTA 0.3f
#define EPS   1e-8f

__device__ __forceinline__ void row_contrib(float x1, float y1, float z1,
                                            float x2, float y2, float z2,
                                            float& a0, float& a1, float& a2,
                                            float& ac) {
    float q1 = x1 * x1 + y1 * y1 + z1 * z1;
    float m = (q1 > EPS * EPS) ? 1.0f : 0.0f;
    float inv1 = (q1 > 0.0f) ? rsqrtf(q1) : 0.0f;
    float n1x = x1 * inv1, n1y = y1 * inv1, n1z = z1 * inv1;

    float q2 = x2 * x2 + y2 * y2 + z2 * z2;
    float inv2 = (q2 > 0.0f) ? rsqrtf(q2) : 0.0f;
    float u2x = x2 * inv2, u2y = y2 * inv2, u2z = z2 * inv2;

    float c = n1x * u2x + n1y * u2y + n1z * u2z;
    c = fminf(1.0f, fmaxf(-1.0f, c));
    float sin_a = sqrtf(fmaxf(0.0f, 1.0f - c * c));
    float cm1 = c - 1.0f;

    float d = n1x * x2 + n1y * y2 + n1z * z2;
    float wx = x2 - n1x * d, wy = y2 - n1y * d, wz = z2 - n1z * d;
    float wq = wx * wx + wy * wy + wz * wz;
    float invw = (wq > 0.0f) ? rsqrtf(wq) : 0.0f;
    float n2x = wx * invw, n2y = wy * invw, n2z = wz * invw;

    float s1 = n1x + n1y + n1z;
    float s2 = n2x + n2y + n2z;

    float tax = sin_a * (n2x * s1 - n1x * s2);
    float tay = sin_a * (n2y * s1 - n1y * s2);
    float taz = sin_a * (n2z * s1 - n1z * s2);

    float tbx = cm1 * (n1x * s1 + n2x * s2);
    float tby = cm1 * (n1y * s1 + n2y * s2);
    float tbz = cm1 * (n1z * s1 + n2z * s2);

    a0 += (ALPHA * tax * tax + BETTA * tbx * tbx) * m;
    a1 += (ALPHA * tay * tay + BETTA * tby * tby) * m;
    a2 += (ALPHA * taz * taz + BETTA * tbz * tbz) * m;
    ac += m;
}

// Stage 1: 8 rows/thread, 6 plain (cached) float4 loads per input issued up
// front. 1024 blocks x 256 threads for N=2^21. NO nontemporal (R4 regression:
// inputs are L2/L3-warm from the harness's d2d restore).
__global__ __launch_bounds__(256) void trl_reduce(const float* __restrict__ v1,
                                                  const float* __restrict__ v2,
                                                  float4* __restrict__ ws,
                                                  int n_rows) {
    int tid = blockIdx.x * blockDim.x + threadIdx.x;
    long row0 = (long)tid * 8;

    float a0 = 0.0f, a1 = 0.0f, a2 = 0.0f, ac = 0.0f;

    if (row0 + 7 < n_rows) {
        const float4* p1 = (const float4*)(v1 + row0 * 3);
        const float4* p2 = (const float4*)(v2 + row0 * 3);
        float4 A[6], B[6];
#pragma unroll
        for (int i = 0; i < 6; ++i) A[i] = p1[i];
#pragma unroll
        for (int i = 0; i < 6; ++i) B[i] = p2[i];

        row_contrib(A[0].x, A[0].y, A[0].z, B[0].x, B[0].y, B[0].z, a0, a1, a2, ac);
        row_contrib(A[0].w, A[1].x, A[1].y, B[0].w, B[1].x, B[1].y, a0, a1, a2, ac);
        row_contrib(A[1].z, A[1].w, A[2].x, B[1].z, B[1].w, B[2].x, a0, a1, a2, ac);
        row_contrib(A[2].y, A[2].z, A[2].w, B[2].y, B[2].z, B[2].w, a0, a1, a2, ac);
        row_contrib(A[3].x, A[3].y, A[3].z, B[3].x, B[3].y, B[3].z, a0, a1, a2, ac);
        row_contrib(A[3].w, A[4].x, A[4].y, B[3].w, B[4].x, B[4].y, a0, a1, a2, ac);
        row_contrib(A[4].z, A[4].w, A[5].x, B[4].z, B[4].w, B[5].x, a0, a1, a2, ac);
        row_contrib(A[5].y, A[5].z, A[5].w, B[5].y, B[5].z, B[5].w, a0, a1, a2, ac);
    } else {
        for (long r = row0; r < n_rows && r < row0 + 8; ++r) {
            const float* q1 = v1 + r * 3;
            const float* q2 = v2 + r * 3;
            row_contrib(q1[0], q1[1], q1[2], q2[0], q2[1], q2[2], a0, a1, a2, ac);
        }
    }

    // wave-64 shuffle reduction
    for (int off = 32; off > 0; off >>= 1) {
        a0 += __shfl_down(a0, off, 64);
        a1 += __shfl_down(a1, off, 64);
        a2 += __shfl_down(a2, off, 64);
        ac += __shfl_down(ac, off, 64);
    }

    __shared__ float smem[4][4];
    int lane = threadIdx.x & 63;
    int wave = threadIdx.x >> 6;
    if (lane == 0) {
        smem[wave][0] = a0;
        smem[wave][1] = a1;
        smem[wave][2] = a2;
        smem[wave][3] = ac;
    }
    __syncthreads();
    if (threadIdx.x == 0) {
        float4 t;
        t.x = smem[0][0] + smem[1][0] + smem[2][0] + smem[3][0];
        t.y = smem[0][1] + smem[1][1] + smem[2][1] + smem[3][1];
        t.z = smem[0][2] + smem[1][2] + smem[2][2] + smem[3][2];
        t.w = smem[0][3] + smem[1][3] + smem[2][3] + smem[3][3];
        ws[blockIdx.x] = t;  // one 16B store per block
    }
}

// Stage 2: single wave, no LDS/barrier. 1024 partials -> 16 float4 per lane.
__global__ __launch_bounds__(64) void trl_final(const float4* __restrict__ ws,
                                                float* __restrict__ out,
                                                int nblocks) {
    int lane = threadIdx.x;
    float s0 = 0.0f, s1 = 0.0f, s2 = 0.0f, sc = 0.0f;
    for (int i = lane; i < nblocks; i += 64) {
        float4 t = ws[i];
        s0 += t.x; s1 += t.y; s2 += t.z; sc += t.w;
    }
    for (int off = 32; off > 0; off >>= 1) {
        s0 += __shfl_down(s0, off, 64);
        s1 += __shfl_down(s1, off, 64);
        s2 += __shfl_down(s2, off, 64);
        sc += __shfl_down(sc, off, 64);
    }
    // lane 0 holds the totals; broadcast via shuffle so lanes 0..2 can store
    float num = (lane == 0) ? s0 : ((lane == 1) ? s1 : s2);
    num = __shfl(num, 0, 64) * 0.0f + num;  // keep per-lane value (no-op)
    if (lane < 3) {
        float n0 = __shfl(s0, 0, 64);
        float n1 = __shfl(s1, 0, 64);
        float n2 = __shfl(s2, 0, 64);
        float ct = __shfl(sc, 0, 64);
        float nums[3] = {n0, n1, n2};
        float cnt = fmaxf(ct, 1.0f);
        float v = nums[lane] / cnt;
        if (isnan(v)) v = 0.0f;
        else if (isinf(v)) v = (v > 0.0f) ? 0.1f : -0.1f;
        out[lane] = v;
    }
}

extern "C" void kernel_launch(void* const* d_in, const int* in_sizes, int n_in,
                              void* d_out, int out_size, void* d_ws, size_t ws_size,
                              hipStream_t stream) {
    const float* v1 = (const float*)d_in[0];
    const float* v2 = (const float*)d_in[1];
    float* out = (float*)d_out;
    float4* ws = (float4*)d_ws;

    int n_rows = in_sizes[0] / 3;

    int block = 256;
    int groups = (n_rows + 7) / 8;            // rows per thread = 8
    int grid = (groups + block - 1) / block;  // 1024 blocks for N=2^21

    trl_reduce<<<grid, block, 0, stream>>>(v1, v2, ws, n_rows);
    trl_final<<<1, 64, 0, stream>>>(ws, out, grid);
}

// Round 6
// 89.866 us; speedup vs baseline: 1.1319x; 1.0661x over previous
//
#include <hip/hip_runtime.h>
#include <math.h>

#define ALPHA 0.7f
#define BETTA 0.3f
#define EPS   1e-8f

#define BLOCK 256
#define ROWS_PER_THREAD 4
#define TILE_ROWS (BLOCK * ROWS_PER_THREAD)   // 1024 rows/block
#define TILE_F4   (TILE_ROWS * 3 / 4)         // 768 float4 per input per tile

__device__ __forceinline__ void row_contrib(float x1, float y1, float z1,
                                            float x2, float y2, float z2,
                                            float& a0, float& a1, float& a2,
                                            float& ac) {
    float q1 = x1 * x1 + y1 * y1 + z1 * z1;
    float m = (q1 > EPS * EPS) ? 1.0f : 0.0f;
    float inv1 = (q1 > 0.0f) ? rsqrtf(q1) : 0.0f;
    float n1x = x1 * inv1, n1y = y1 * inv1, n1z = z1 * inv1;

    float q2 = x2 * x2 + y2 * y2 + z2 * z2;
    float inv2 = (q2 > 0.0f) ? rsqrtf(q2) : 0.0f;
    float u2x = x2 * inv2, u2y = y2 * inv2, u2z = z2 * inv2;

    float c = n1x * u2x + n1y * u2y + n1z * u2z;
    c = fminf(1.0f, fmaxf(-1.0f, c));
    float sin_a = sqrtf(fmaxf(0.0f, 1.0f - c * c));
    float cm1 = c - 1.0f;

    float d = n1x * x2 + n1y * y2 + n1z * z2;
    float wx = x2 - n1x * d, wy = y2 - n1y * d, wz = z2 - n1z * d;
    float wq = wx * wx + wy * wy + wz * wz;
    float invw = (wq > 0.0f) ? rsqrtf(wq) : 0.0f;
    float n2x = wx * invw, n2y = wy * invw, n2z = wz * invw;

    float s1 = n1x + n1y + n1z;
    float s2 = n2x + n2y + n2z;

    float tax = sin_a * (n2x * s1 - n1x * s2);
    float tay = sin_a * (n2y * s1 - n1y * s2);
    float taz = sin_a * (n2z * s1 - n1z * s2);

    float tbx = cm1 * (n1x * s1 + n2x * s2);
    float tby = cm1 * (n1y * s1 + n2y * s2);
    float tbz = cm1 * (n1z * s1 + n2z * s2);

    a0 += (ALPHA * tax * tax + BETTA * tbx * tbx) * m;
    a1 += (ALPHA * tay * tay + BETTA * tby * tby) * m;
    a2 += (ALPHA * taz * taz + BETTA * tbz * tbz) * m;
    ac += m;
}

// Stage 1: coalesced global float4 loads (lane i reads tileBase + j*256 + i,
// unit stride across the wave) staged through LDS; each thread then reads its
// 4 rows (48B) from LDS. Fixes the 96B-strided global pattern that held
// trl_reduce at ~1.7 TB/s (R2==R5 wall).
__global__ __launch_bounds__(BLOCK) void trl_reduce(const float* __restrict__ v1,
                                                    const float* __restrict__ v2,
                                                    float4* __restrict__ ws,
                                                    int n_rows) {
    __shared__ float4 ldsA[TILE_F4];  // 12 KB
    __shared__ float4 ldsB[TILE_F4];  // 12 KB

    int t = threadIdx.x;
    long tile_row0 = (long)blockIdx.x * TILE_ROWS;

    float a0 = 0.0f, a1 = 0.0f, a2 = 0.0f, ac = 0.0f;

    if (tile_row0 + TILE_ROWS <= n_rows) {
        const float4* g1 = (const float4*)v1;
        const float4* g2 = (const float4*)v2;
        long base = (long)blockIdx.x * TILE_F4;

        // issue all 6 coalesced loads up front for MLP
        float4 la0 = g1[base + 0 * BLOCK + t];
        float4 la1 = g1[base + 1 * BLOCK + t];
        float4 la2 = g1[base + 2 * BLOCK + t];
        float4 lb0 = g2[base + 0 * BLOCK + t];
        float4 lb1 = g2[base + 1 * BLOCK + t];
        float4 lb2 = g2[base + 2 * BLOCK + t];

        ldsA[0 * BLOCK + t] = la0;
        ldsA[1 * BLOCK + t] = la1;
        ldsA[2 * BLOCK + t] = la2;
        ldsB[0 * BLOCK + t] = lb0;
        ldsB[1 * BLOCK + t] = lb1;
        ldsB[2 * BLOCK + t] = lb2;
        __syncthreads();

        float4 A0 = ldsA[3 * t + 0];
        float4 A1 = ldsA[3 * t + 1];
        float4 A2 = ldsA[3 * t + 2];
        float4 B0 = ldsB[3 * t + 0];
        float4 B1 = ldsB[3 * t + 1];
        float4 B2 = ldsB[3 * t + 2];

        row_contrib(A0.x, A0.y, A0.z, B0.x, B0.y, B0.z, a0, a1, a2, ac);
        row_contrib(A0.w, A1.x, A1.y, B0.w, B1.x, B1.y, a0, a1, a2, ac);
        row_contrib(A1.z, A1.w, A2.x, B1.z, B1.w, B2.x, a0, a1, a2, ac);
        row_contrib(A2.y, A2.z, A2.w, B2.y, B2.z, B2.w, a0, a1, a2, ac);
    } else {
        // scalar tail (unused for N=2^21; kept for generality)
        long row0 = tile_row0 + (long)t * ROWS_PER_THREAD;
        for (long r = row0; r < n_rows && r < row0 + ROWS_PER_THREAD; ++r) {
            const float* q1 = v1 + r * 3;
            const float* q2 = v2 + r * 3;
            row_contrib(q1[0], q1[1], q1[2], q2[0], q2[1], q2[2], a0, a1, a2, ac);
        }
    }

    // wave-64 shuffle reduction
    for (int off = 32; off > 0; off >>= 1) {
        a0 += __shfl_down(a0, off, 64);
        a1 += __shfl_down(a1, off, 64);
        a2 += __shfl_down(a2, off, 64);
        ac += __shfl_down(ac, off, 64);
    }

    __shared__ float smem[4][4];
    int lane = t & 63;
    int wave = t >> 6;
    if (lane == 0) {
        smem[wave][0] = a0;
        smem[wave][1] = a1;
        smem[wave][2] = a2;
        smem[wave][3] = ac;
    }
    __syncthreads();
    if (t == 0) {
        float4 o;
        o.x = smem[0][0] + smem[1][0] + smem[2][0] + smem[3][0];
        o.y = smem[0][1] + smem[1][1] + smem[2][1] + smem[3][1];
        o.z = smem[0][2] + smem[1][2] + smem[2][2] + smem[3][2];
        o.w = smem[0][3] + smem[1][3] + smem[2][3] + smem[3][3];
        ws[blockIdx.x] = o;
    }
}

// Stage 2: one 256-thread block; threads stride over the float4 partials.
__global__ __launch_bounds__(256) void trl_final(const float4* __restrict__ ws,
                                                 float* __restrict__ out,
                                                 int nblocks) {
    float s0 = 0.0f, s1 = 0.0f, s2 = 0.0f, sc = 0.0f;
    for (int i = threadIdx.x; i < nblocks; i += 256) {
        float4 p = ws[i];
        s0 += p.x; s1 += p.y; s2 += p.z; sc += p.w;
    }
    for (int off = 32; off > 0; off >>= 1) {
        s0 += __shfl_down(s0, off, 64);
        s1 += __shfl_down(s1, off, 64);
        s2 += __shfl_down(s2, off, 64);
        sc += __shfl_down(sc, off, 64);
    }
    __shared__ float smem[4][4];
    int lane = threadIdx.x & 63;
    int wave = threadIdx.x >> 6;
    if (lane == 0) {
        smem[wave][0] = s0;
        smem[wave][1] = s1;
        smem[wave][2] = s2;
        smem[wave][3] = sc;
    }
    __syncthreads();
    if (threadIdx.x < 3) {
        float num = smem[0][threadIdx.x] + smem[1][threadIdx.x] +
                    smem[2][threadIdx.x] + smem[3][threadIdx.x];
        float cnt = smem[0][3] + smem[1][3] + smem[2][3] + smem[3][3];
        cnt = fmaxf(cnt, 1.0f);
        float v = num / cnt;
        if (isnan(v)) v = 0.0f;
        else if (isinf(v)) v = (v > 0.0f) ? 0.1f : -0.1f;
        out[threadIdx.x] = v;
    }
}

extern "C" void kernel_launch(void* const* d_in, const int* in_sizes, int n_in,
                              void* d_out, int out_size, void* d_ws, size_t ws_size,
                              hipStream_t stream) {
    const float* v1 = (const float*)d_in[0];
    const float* v2 = (const float*)d_in[1];
    float* out = (float*)d_out;
    float4* ws = (float4*)d_ws;

    int n_rows = in_sizes[0] / 3;

    int grid = (n_rows + TILE_ROWS - 1) / TILE_ROWS;  // 2048 blocks for N=2^21

    trl_reduce<<<grid, BLOCK, 0, stream>>>(v1, v2, ws, n_rows);
    trl_final<<<1, 256, 0, stream>>>(ws, out, grid);
}